// Round 4
// baseline (1073.106 us; speedup 1.0000x reference)
//
#include <hip/hip_runtime.h>

#define NU 100000
#define NI 50000
#define NE 1000000
#define NB 16384

#define UB ((NU + 1023) / 1024)   // 98 user scan blocks
#define IB ((NI + 1023) / 1024)   // 49 item scan blocks

// ---- degree count (int atomics) ----
__global__ void deg_kernel(const int* __restrict__ ei, int* du, int* di) {
    int e = blockIdx.x * blockDim.x + threadIdx.x;
    if (e >= NE) return;
    atomicAdd(&du[ei[e]], 1);
    atomicAdd(&di[ei[NE + e]], 1);
}

// ---- scan pass 1: per-block partial sums (+ fused rsd computation) ----
__global__ __launch_bounds__(1024) void scan1_kernel(
        const int* __restrict__ du, const int* __restrict__ di,
        int* __restrict__ psum, float* __restrict__ rsd_u, float* __restrict__ rsd_i) {
    int b = blockIdx.x, tid = threadIdx.x;
    int v = 0;
    if (b < UB) {
        int i = b * 1024 + tid;
        if (i < NU) {
            int d = du[i]; v = d;
            rsd_u[i] = d > 0 ? 1.0f / sqrtf((float)d) : 0.f;
        }
    } else {
        int i = (b - UB) * 1024 + tid;
        if (i < NI) {
            int d = di[i]; v = d;
            rsd_i[i] = d > 0 ? 1.0f / sqrtf((float)d) : 0.f;
        }
    }
    int s = v;
    #pragma unroll
    for (int off = 32; off > 0; off >>= 1) s += __shfl_xor(s, off);
    __shared__ int ws[16];
    if ((tid & 63) == 0) ws[tid >> 6] = s;
    __syncthreads();
    if (tid == 0) {
        int t = 0;
        #pragma unroll
        for (int w = 0; w < 16; ++w) t += ws[w];
        psum[b] = t;
    }
}

// ---- scan pass 2: exclusive scan of block partials (per segment) ----
__global__ __launch_bounds__(128) void scan2_kernel(int* __restrict__ psum) {
    int base = (blockIdx.x == 0) ? 0 : UB;
    int n = (blockIdx.x == 0) ? UB : IB;
    int tid = threadIdx.x;
    __shared__ int sh[128];
    int v = (tid < n) ? psum[base + tid] : 0;
    sh[tid] = v;
    __syncthreads();
    for (int off = 1; off < 128; off <<= 1) {
        int t = (tid >= off) ? sh[tid - off] : 0;
        __syncthreads();
        sh[tid] += t;
        __syncthreads();
    }
    if (tid < n) psum[base + tid] = sh[tid] - v;  // exclusive
}

// ---- scan pass 3: block-local exclusive scan + offset -> rowptr, cursor ----
__global__ __launch_bounds__(1024) void scan3_kernel(
        const int* __restrict__ du, const int* __restrict__ di,
        const int* __restrict__ psum,
        int* __restrict__ rp_u, int* __restrict__ rp_i,
        int* __restrict__ cur_u, int* __restrict__ cur_i) {
    int b = blockIdx.x, tid = threadIdx.x;
    const int* deg; int* rp; int* cur; int N; int i0;
    if (b < UB) { deg = du; rp = rp_u; cur = cur_u; N = NU; i0 = b * 1024; }
    else        { deg = di; rp = rp_i; cur = cur_i; N = NI; i0 = (b - UB) * 1024; }
    int i = i0 + tid;
    int v = (i < N) ? deg[i] : 0;
    __shared__ int sh[1024];
    sh[tid] = v;
    __syncthreads();
    for (int off = 1; off < 1024; off <<= 1) {
        int t = (tid >= off) ? sh[tid - off] : 0;
        __syncthreads();
        sh[tid] += t;
        __syncthreads();
    }
    int excl = sh[tid] - v + psum[b];
    if (i < N) { rp[i] = excl; cur[i] = excl; }
    if (b == 0 && tid == 0) { rp_u[NU] = NE; rp_i[NI] = NE; }
}

// ---- CSR fill: 2M int atomics ----
__global__ void fill_csr_kernel(const int* __restrict__ ei,
                                int* __restrict__ curu, int* __restrict__ curi,
                                int* __restrict__ csr_u, int* __restrict__ csr_i) {
    int e = blockIdx.x * blockDim.x + threadIdx.x;
    if (e >= NE) return;
    int s = ei[e], d = ei[NE + e];
    int si = atomicAdd(&curi[d], 1);
    csr_i[si] = s;
    int su = atomicAdd(&curu[s], 1);
    csr_u[su] = d;
}

// ---- fused gather + transform + epilogue, 4 nodes per wave ----
// Weight LDS traffic amortized 4x; W^T stored chunk-XOR-swizzled so the
// b128 column reads are bank-conflict-free (linear W^T would be 64-way).
#define BATCH 4
__global__ __launch_bounds__(512) void gt_fused_kernel(
        const float* __restrict__ xu, const float* __restrict__ xi,
        const int* __restrict__ rpu, const int* __restrict__ rpi,
        const int* __restrict__ csru, const int* __restrict__ csri,
        const float* __restrict__ rsdu, const float* __restrict__ rsdi,
        const float* __restrict__ W1, const float* __restrict__ b1,
        const float* __restrict__ W2, const float* __restrict__ b2,
        float* __restrict__ outu, float* __restrict__ outi) {
    __shared__ float wt1[64 * 64];            // wt1[d][k] = W1[k][d], swizzled
    __shared__ float wt2[64 * 64];
    __shared__ float acs[8][BATCH][128];      // per-wave a||c slabs (16 KB)
    int tid = threadIdx.x;
    // stage + transpose + swizzle: element (k,d) -> d*64 + ((k>>2)^(d&7))*4 + (k&3)
    #pragma unroll
    for (int r = 0; r < 8; ++r) {
        int e = r * 512 + tid;
        int k = e >> 6, d = e & 63;
        int dst = d * 64 + (((k >> 2) ^ (d & 7)) << 2) + (k & 3);
        wt1[dst] = W1[e];
        wt2[dst] = W2[e];
    }
    __syncthreads();
    int wv = tid >> 6, lane = tid & 63;
    float b1v = b1[lane], b2v = b2[lane];
    int wrow = lane * 64;                     // this lane's W^T row base
    const int NG = (NI + NU + 31) / 32;       // 32 nodes per block-group
    for (int g = blockIdx.x; g < NG; g += gridDim.x) {
        int nbase = g * 32 + wv * BATCH;
        float ba[BATCH], dg[BATCH];
        // ---- gather phase: 4 nodes sequentially ----
        #pragma unroll
        for (int j = 0; j < BATCH; ++j) {
            int n = nbase + j;
            bool act = n < NI + NU;
            bool isItem = n < NI;
            int nn = isItem ? n : n - NI;
            const int* rp     = isItem ? rpi : rpu;
            const int* cs     = isItem ? csri : csru;
            const float* xin  = isItem ? xi : xu;
            const float* embo = isItem ? xu : xi;
            const float* rso  = isItem ? rsdu : rsdi;
            const float* rown = isItem ? rsdi : rsdu;
            float sp = 0.f, ss = 0.f, sw = 0.f, rs = 0.f, dgf = 0.f, xv = 0.f;
            if (act) {
                int beg = rp[nn], end = rp[nn + 1];
                dgf = (float)(end - beg);
                rs = rown[nn];
                xv = xin[nn * 64 + lane];
                int jj = beg;
                for (; jj + 3 < end; jj += 4) {
                    int i0 = cs[jj], i1 = cs[jj + 1], i2 = cs[jj + 2], i3 = cs[jj + 3];
                    float w0 = rso[i0], w1v = rso[i1], w2v = rso[i2], w3v = rso[i3];
                    float v0 = embo[i0 * 64 + lane];
                    float v1 = embo[i1 * 64 + lane];
                    float v2 = embo[i2 * 64 + lane];
                    float v3 = embo[i3 * 64 + lane];
                    sp += (v0 + v1) + (v2 + v3);
                    ss += w0 * v0 + w1v * v1 + w2v * v2 + w3v * v3;
                    sw += (w0 + w1v) + (w2v + w3v);
                }
                for (; jj < end; ++jj) {
                    int i0 = cs[jj];
                    float w0 = rso[i0];
                    float v0 = embo[i0 * 64 + lane];
                    sp += v0; ss += w0 * v0; sw += w0;
                }
            }
            ba[j] = rs * sw;
            dg[j] = dgf;
            acs[wv][j][lane] = rs * ss;
            acs[wv][j][64 + lane] = xv * sp;
        }
        // ---- matmul phase: W read once per 4 nodes, b128 everywhere ----
        float acc[BATCH] = {0.f, 0.f, 0.f, 0.f};
        int sw8 = (lane & 7);
        #pragma unroll 4
        for (int c = 0; c < 16; ++c) {
            float4 w1v = *(const float4*)&wt1[wrow + ((c ^ sw8) << 2)];
            float4 w2v = *(const float4*)&wt2[wrow + ((c ^ sw8) << 2)];
            #pragma unroll
            for (int j = 0; j < BATCH; ++j) {
                float4 av = *(const float4*)&acs[wv][j][c * 4];
                float4 cv = *(const float4*)&acs[wv][j][64 + c * 4];
                acc[j] += av.x * w1v.x + av.y * w1v.y + av.z * w1v.z + av.w * w1v.w
                        + cv.x * w2v.x + cv.y * w2v.y + cv.z * w2v.z + cv.w * w2v.w;
            }
        }
        // ---- epilogue per node ----
        #pragma unroll
        for (int j = 0; j < BATCH; ++j) {
            int n = nbase + j;
            if (n >= NI + NU) continue;
            bool isItem = n < NI;
            int nn = isItem ? n : n - NI;
            float* outp = isItem ? outi : outu;
            float h = acc[j] + ba[j] * b1v + dg[j] * b2v;
            h = h >= 0.f ? h : 0.2f * h;
            float nsq = h * h;
            #pragma unroll
            for (int off = 32; off > 0; off >>= 1) nsq += __shfl_xor(nsq, off);
            float nrm = sqrtf(nsq);
            outp[nn * 64 + lane] = h / fmaxf(nrm, 1e-12f);
        }
    }
}

// ---- final gather of concatenated embeddings (float4) ----
__global__ void gather_kernel(const float* __restrict__ ue, const float* __restrict__ u1,
                              const float* __restrict__ u2, const float* __restrict__ ie,
                              const float* __restrict__ i1, const float* __restrict__ i2,
                              const int* __restrict__ users, const int* __restrict__ pos,
                              const int* __restrict__ neg, float4* __restrict__ out) {
    int idx = blockIdx.x * blockDim.x + threadIdx.x;     // float4 index
    if (idx >= 3 * NB * 48) return;
    int which = idx / (NB * 48);
    int rem = idx - which * (NB * 48);
    int b = rem / 48, c4 = rem - b * 48;                 // c4 in [0,48): float4 within row
    int seg = c4 >> 4, cc = (c4 & 15) << 2;
    int row;
    const float* srcarr;
    if (which == 0) {
        row = users[b];
        srcarr = (seg == 0) ? ue : (seg == 1 ? u1 : u2);
    } else {
        row = (which == 1) ? pos[b] : neg[b];
        srcarr = (seg == 0) ? ie : (seg == 1 ? i1 : i2);
    }
    out[idx] = *(const float4*)&srcarr[(size_t)row * 64 + cc];
}

extern "C" void kernel_launch(void* const* d_in, const int* in_sizes, int n_in,
                              void* d_out, int out_size, void* d_ws, size_t ws_size,
                              hipStream_t stream) {
    const float* user_emb = (const float*)d_in[0];
    const float* item_emb = (const float*)d_in[1];
    const float* W1_0 = (const float*)d_in[2];
    const float* b1_0 = (const float*)d_in[3];
    const float* W2_0 = (const float*)d_in[4];
    const float* b2_0 = (const float*)d_in[5];
    const float* W1_1 = (const float*)d_in[6];
    const float* b1_1 = (const float*)d_in[7];
    const float* W2_1 = (const float*)d_in[8];
    const float* b2_1 = (const float*)d_in[9];
    const int* ei = (const int*)d_in[10];
    const int* users = (const int*)d_in[11];
    const int* pos = (const int*)d_in[12];
    const int* neg = (const int*)d_in[13];

    char* p = (char*)d_ws;
    int* du = (int*)p;        p += NU * 4;
    int* di = (int*)p;        p += NI * 4;
    float* rsd_u = (float*)p; p += NU * 4;
    float* rsd_i = (float*)p; p += NI * 4;
    int* psum = (int*)p;      p += (UB + IB) * 4;
    int* rp_u = (int*)p;      p += (NU + 1) * 4;
    int* rp_i = (int*)p;      p += (NI + 1) * 4;
    int* cur_u = (int*)p;     p += NU * 4;
    int* cur_i = (int*)p;     p += NI * 4;
    int* csr_u = (int*)p;     p += (size_t)NE * 4;
    int* csr_i = (int*)p;     p += (size_t)NE * 4;
    float* u1 = (float*)p;    p += (size_t)NU * 64 * 4;
    float* u2 = (float*)p;    p += (size_t)NU * 64 * 4;
    float* i1 = (float*)p;    p += (size_t)NI * 64 * 4;
    float* i2 = (float*)p;    p += (size_t)NI * 64 * 4;

    // zero the degree counters (ws is re-poisoned before every call)
    hipMemsetAsync(du, 0, (size_t)(NU + NI) * sizeof(int), stream);

    deg_kernel<<<(NE + 255) / 256, 256, 0, stream>>>(ei, du, di);
    scan1_kernel<<<UB + IB, 1024, 0, stream>>>(du, di, psum, rsd_u, rsd_i);
    scan2_kernel<<<2, 128, 0, stream>>>(psum);
    scan3_kernel<<<UB + IB, 1024, 0, stream>>>(du, di, psum, rp_u, rp_i, cur_u, cur_i);
    fill_csr_kernel<<<(NE + 255) / 256, 256, 0, stream>>>(ei, cur_u, cur_i, csr_u, csr_i);

    // ---- layer 0 ----
    gt_fused_kernel<<<2048, 512, 0, stream>>>(user_emb, item_emb, rp_u, rp_i, csr_u, csr_i,
                                              rsd_u, rsd_i, W1_0, b1_0, W2_0, b2_0, u1, i1);
    // ---- layer 1 ----
    gt_fused_kernel<<<2048, 512, 0, stream>>>(u1, i1, rp_u, rp_i, csr_u, csr_i,
                                              rsd_u, rsd_i, W1_1, b1_1, W2_1, b2_1, u2, i2);

    // ---- final gather ----
    gather_kernel<<<(3 * NB * 48 + 255) / 256, 256, 0, stream>>>(
        user_emb, u1, u2, item_emb, i1, i2, users, pos, neg, (float4*)d_out);
}

// Round 5
// 787.580 us; speedup vs baseline: 1.3625x; 1.3625x over previous
//
#include <hip/hip_runtime.h>

#define NU 100000
#define NI 50000
#define NE 1000000
#define NB 16384

#define UB ((NU + 1023) / 1024)   // 98 user scan blocks
#define IB ((NI + 1023) / 1024)   // 49 item scan blocks

// ---- degree count (int atomics) ----
__global__ void deg_kernel(const int* __restrict__ ei, int* du, int* di) {
    int e = blockIdx.x * blockDim.x + threadIdx.x;
    if (e >= NE) return;
    atomicAdd(&du[ei[e]], 1);
    atomicAdd(&di[ei[NE + e]], 1);
}

// ---- scan pass 1: per-block partial sums (+ fused rsd computation) ----
__global__ __launch_bounds__(1024) void scan1_kernel(
        const int* __restrict__ du, const int* __restrict__ di,
        int* __restrict__ psum, float* __restrict__ rsd_u, float* __restrict__ rsd_i) {
    int b = blockIdx.x, tid = threadIdx.x;
    int v = 0;
    if (b < UB) {
        int i = b * 1024 + tid;
        if (i < NU) {
            int d = du[i]; v = d;
            rsd_u[i] = d > 0 ? 1.0f / sqrtf((float)d) : 0.f;
        }
    } else {
        int i = (b - UB) * 1024 + tid;
        if (i < NI) {
            int d = di[i]; v = d;
            rsd_i[i] = d > 0 ? 1.0f / sqrtf((float)d) : 0.f;
        }
    }
    int s = v;
    #pragma unroll
    for (int off = 32; off > 0; off >>= 1) s += __shfl_xor(s, off);
    __shared__ int ws[16];
    if ((tid & 63) == 0) ws[tid >> 6] = s;
    __syncthreads();
    if (tid == 0) {
        int t = 0;
        #pragma unroll
        for (int w = 0; w < 16; ++w) t += ws[w];
        psum[b] = t;
    }
}

// ---- scan pass 2: exclusive scan of block partials (per segment) ----
__global__ __launch_bounds__(128) void scan2_kernel(int* __restrict__ psum) {
    int base = (blockIdx.x == 0) ? 0 : UB;
    int n = (blockIdx.x == 0) ? UB : IB;
    int tid = threadIdx.x;
    __shared__ int sh[128];
    int v = (tid < n) ? psum[base + tid] : 0;
    sh[tid] = v;
    __syncthreads();
    for (int off = 1; off < 128; off <<= 1) {
        int t = (tid >= off) ? sh[tid - off] : 0;
        __syncthreads();
        sh[tid] += t;
        __syncthreads();
    }
    if (tid < n) psum[base + tid] = sh[tid] - v;  // exclusive
}

// ---- scan pass 3: block-local exclusive scan + offset -> rowptr, cursor ----
__global__ __launch_bounds__(1024) void scan3_kernel(
        const int* __restrict__ du, const int* __restrict__ di,
        const int* __restrict__ psum,
        int* __restrict__ rp_u, int* __restrict__ rp_i,
        int* __restrict__ cur_u, int* __restrict__ cur_i) {
    int b = blockIdx.x, tid = threadIdx.x;
    const int* deg; int* rp; int* cur; int N; int i0;
    if (b < UB) { deg = du; rp = rp_u; cur = cur_u; N = NU; i0 = b * 1024; }
    else        { deg = di; rp = rp_i; cur = cur_i; N = NI; i0 = (b - UB) * 1024; }
    int i = i0 + tid;
    int v = (i < N) ? deg[i] : 0;
    __shared__ int sh[1024];
    sh[tid] = v;
    __syncthreads();
    for (int off = 1; off < 1024; off <<= 1) {
        int t = (tid >= off) ? sh[tid - off] : 0;
        __syncthreads();
        sh[tid] += t;
        __syncthreads();
    }
    int excl = sh[tid] - v + psum[b];
    if (i < N) { rp[i] = excl; cur[i] = excl; }
    if (b == 0 && tid == 0) { rp_u[NU] = NE; rp_i[NI] = NE; }
}

// ---- CSR fill: 2M int atomics ----
__global__ void fill_csr_kernel(const int* __restrict__ ei,
                                int* __restrict__ curu, int* __restrict__ curi,
                                int* __restrict__ csr_u, int* __restrict__ csr_i) {
    int e = blockIdx.x * blockDim.x + threadIdx.x;
    if (e >= NE) return;
    int s = ei[e], d = ei[NE + e];
    int si = atomicAdd(&curi[d], 1);
    csr_i[si] = s;
    int su = atomicAdd(&curu[s], 1);
    csr_u[su] = d;
}

// ---- fused gather + transform + epilogue, 4 nodes per wave ----
// W kept in VERBATIM k-major layout: w[k*64+lane] is stride-1 across lanes
// -> zero bank conflicts by construction (R4's transposed+swizzled layout
// was ~8-way conflicted: 6.37M SQ_LDS_BANK_CONFLICT). W read once per k is
// reused for 4 nodes held in registers -> 4x less W LDS traffic than R3.
#define BATCH 4
__global__ __launch_bounds__(512) void gt_fused_kernel(
        const float* __restrict__ xu, const float* __restrict__ xi,
        const int* __restrict__ rpu, const int* __restrict__ rpi,
        const int* __restrict__ csru, const int* __restrict__ csri,
        const float* __restrict__ rsdu, const float* __restrict__ rsdi,
        const float* __restrict__ W1, const float* __restrict__ b1,
        const float* __restrict__ W2, const float* __restrict__ b2,
        float* __restrict__ outu, float* __restrict__ outi) {
    __shared__ float w1s[64 * 64];            // verbatim: w1s[k*64+d]
    __shared__ float w2s[64 * 64];
    __shared__ float acs[8][BATCH][128];      // per-wave a||c slabs (16 KB)
    int tid = threadIdx.x;
    #pragma unroll
    for (int r = 0; r < 8; ++r) {
        w1s[r * 512 + tid] = W1[r * 512 + tid];
        w2s[r * 512 + tid] = W2[r * 512 + tid];
    }
    __syncthreads();
    int wv = tid >> 6, lane = tid & 63;
    float b1v = b1[lane], b2v = b2[lane];
    const int NG = (NI + NU + 31) / 32;       // 32 nodes per block-group
    for (int g = blockIdx.x; g < NG; g += gridDim.x) {
        int nbase = g * 32 + wv * BATCH;
        float ba[BATCH], dg[BATCH];
        // ---- gather phase: 4 nodes, unroll-4 neighbors each ----
        #pragma unroll
        for (int j = 0; j < BATCH; ++j) {
            int n = nbase + j;
            bool act = n < NI + NU;
            bool isItem = n < NI;
            int nn = isItem ? n : n - NI;
            const int* rp     = isItem ? rpi : rpu;
            const int* cs     = isItem ? csri : csru;
            const float* xin  = isItem ? xi : xu;
            const float* embo = isItem ? xu : xi;
            const float* rso  = isItem ? rsdu : rsdi;
            const float* rown = isItem ? rsdi : rsdu;
            float sp = 0.f, ss = 0.f, sw = 0.f, rs = 0.f, dgf = 0.f, xv = 0.f;
            if (act) {
                int beg = rp[nn], end = rp[nn + 1];
                dgf = (float)(end - beg);
                rs = rown[nn];
                xv = xin[nn * 64 + lane];
                int jj = beg;
                for (; jj + 3 < end; jj += 4) {
                    int i0 = cs[jj], i1 = cs[jj + 1], i2 = cs[jj + 2], i3 = cs[jj + 3];
                    float w0 = rso[i0], w1v = rso[i1], w2v = rso[i2], w3v = rso[i3];
                    float v0 = embo[i0 * 64 + lane];
                    float v1 = embo[i1 * 64 + lane];
                    float v2 = embo[i2 * 64 + lane];
                    float v3 = embo[i3 * 64 + lane];
                    sp += (v0 + v1) + (v2 + v3);
                    ss += w0 * v0 + w1v * v1 + w2v * v2 + w3v * v3;
                    sw += (w0 + w1v) + (w2v + w3v);
                }
                for (; jj < end; ++jj) {
                    int i0 = cs[jj];
                    float w0 = rso[i0];
                    float v0 = embo[i0 * 64 + lane];
                    sp += v0; ss += w0 * v0; sw += w0;
                }
            }
            ba[j] = rs * sw;
            dg[j] = dgf;
            acs[wv][j][lane] = rs * ss;
            acs[wv][j][64 + lane] = xv * sp;
        }
        // ---- matmul phase: each W element read once per 4 nodes ----
        float acc[BATCH] = {0.f, 0.f, 0.f, 0.f};
        #pragma unroll 4
        for (int kq = 0; kq < 16; ++kq) {     // k-quads
            float4 av[BATCH], cv[BATCH];
            #pragma unroll
            for (int j = 0; j < BATCH; ++j) {
                av[j] = *(const float4*)&acs[wv][j][kq * 4];        // broadcast
                cv[j] = *(const float4*)&acs[wv][j][64 + kq * 4];   // broadcast
            }
            #pragma unroll
            for (int kk = 0; kk < 4; ++kk) {
                int k = kq * 4 + kk;
                float w1v = w1s[k * 64 + lane];   // stride-1: conflict-free
                float w2v = w2s[k * 64 + lane];
                #pragma unroll
                for (int j = 0; j < BATCH; ++j) {
                    float a = (&av[j].x)[kk], c = (&cv[j].x)[kk];
                    acc[j] += a * w1v + c * w2v;
                }
            }
        }
        // ---- epilogue per node ----
        #pragma unroll
        for (int j = 0; j < BATCH; ++j) {
            int n = nbase + j;
            if (n >= NI + NU) continue;
            bool isItem = n < NI;
            int nn = isItem ? n : n - NI;
            float* outp = isItem ? outi : outu;
            float h = acc[j] + ba[j] * b1v + dg[j] * b2v;
            h = h >= 0.f ? h : 0.2f * h;
            float nsq = h * h;
            #pragma unroll
            for (int off = 32; off > 0; off >>= 1) nsq += __shfl_xor(nsq, off);
            float nrm = sqrtf(nsq);
            outp[nn * 64 + lane] = h / fmaxf(nrm, 1e-12f);
        }
    }
}

// ---- final gather of concatenated embeddings (float4) ----
__global__ void gather_kernel(const float* __restrict__ ue, const float* __restrict__ u1,
                              const float* __restrict__ u2, const float* __restrict__ ie,
                              const float* __restrict__ i1, const float* __restrict__ i2,
                              const int* __restrict__ users, const int* __restrict__ pos,
                              const int* __restrict__ neg, float4* __restrict__ out) {
    int idx = blockIdx.x * blockDim.x + threadIdx.x;     // float4 index
    if (idx >= 3 * NB * 48) return;
    int which = idx / (NB * 48);
    int rem = idx - which * (NB * 48);
    int b = rem / 48, c4 = rem - b * 48;                 // c4 in [0,48)
    int seg = c4 >> 4, cc = (c4 & 15) << 2;
    int row;
    const float* srcarr;
    if (which == 0) {
        row = users[b];
        srcarr = (seg == 0) ? ue : (seg == 1 ? u1 : u2);
    } else {
        row = (which == 1) ? pos[b] : neg[b];
        srcarr = (seg == 0) ? ie : (seg == 1 ? i1 : i2);
    }
    out[idx] = *(const float4*)&srcarr[(size_t)row * 64 + cc];
}

extern "C" void kernel_launch(void* const* d_in, const int* in_sizes, int n_in,
                              void* d_out, int out_size, void* d_ws, size_t ws_size,
                              hipStream_t stream) {
    const float* user_emb = (const float*)d_in[0];
    const float* item_emb = (const float*)d_in[1];
    const float* W1_0 = (const float*)d_in[2];
    const float* b1_0 = (const float*)d_in[3];
    const float* W2_0 = (const float*)d_in[4];
    const float* b2_0 = (const float*)d_in[5];
    const float* W1_1 = (const float*)d_in[6];
    const float* b1_1 = (const float*)d_in[7];
    const float* W2_1 = (const float*)d_in[8];
    const float* b2_1 = (const float*)d_in[9];
    const int* ei = (const int*)d_in[10];
    const int* users = (const int*)d_in[11];
    const int* pos = (const int*)d_in[12];
    const int* neg = (const int*)d_in[13];

    char* p = (char*)d_ws;
    int* du = (int*)p;        p += NU * 4;
    int* di = (int*)p;        p += NI * 4;
    float* rsd_u = (float*)p; p += NU * 4;
    float* rsd_i = (float*)p; p += NI * 4;
    int* psum = (int*)p;      p += (UB + IB) * 4;
    int* rp_u = (int*)p;      p += (NU + 1) * 4;
    int* rp_i = (int*)p;      p += (NI + 1) * 4;
    int* cur_u = (int*)p;     p += NU * 4;
    int* cur_i = (int*)p;     p += NI * 4;
    int* csr_u = (int*)p;     p += (size_t)NE * 4;
    int* csr_i = (int*)p;     p += (size_t)NE * 4;
    float* u1 = (float*)p;    p += (size_t)NU * 64 * 4;
    float* u2 = (float*)p;    p += (size_t)NU * 64 * 4;
    float* i1 = (float*)p;    p += (size_t)NI * 64 * 4;
    float* i2 = (float*)p;    p += (size_t)NI * 64 * 4;

    // zero the degree counters (ws is re-poisoned before every call)
    hipMemsetAsync(du, 0, (size_t)(NU + NI) * sizeof(int), stream);

    deg_kernel<<<(NE + 255) / 256, 256, 0, stream>>>(ei, du, di);
    scan1_kernel<<<UB + IB, 1024, 0, stream>>>(du, di, psum, rsd_u, rsd_i);
    scan2_kernel<<<2, 128, 0, stream>>>(psum);
    scan3_kernel<<<UB + IB, 1024, 0, stream>>>(du, di, psum, rp_u, rp_i, cur_u, cur_i);
    fill_csr_kernel<<<(NE + 255) / 256, 256, 0, stream>>>(ei, cur_u, cur_i, csr_u, csr_i);

    // ---- layer 0 ----
    gt_fused_kernel<<<2048, 512, 0, stream>>>(user_emb, item_emb, rp_u, rp_i, csr_u, csr_i,
                                              rsd_u, rsd_i, W1_0, b1_0, W2_0, b2_0, u1, i1);
    // ---- layer 1 ----
    gt_fused_kernel<<<2048, 512, 0, stream>>>(u1, i1, rp_u, rp_i, csr_u, csr_i,
                                              rsd_u, rsd_i, W1_1, b1_1, W2_1, b2_1, u2, i2);

    // ---- final gather ----
    gather_kernel<<<(3 * NB * 48 + 255) / 256, 256, 0, stream>>>(
        user_emb, u1, u2, item_emb, i1, i2, users, pos, neg, (float4*)d_out);
}